// Round 1
// baseline (8539.315 us; speedup 1.0000x reference)
//
#include <hip/hip_runtime.h>
#include <cstddef>

#define LN_EPS 1e-3f

// ---------------------------------------------------------------------------
// LayerNorm over last dim C=16 (one thread per row of 16)
// ---------------------------------------------------------------------------
__global__ void ln16_kernel(const float* __restrict__ x, const float* __restrict__ g,
                            const float* __restrict__ b, float* __restrict__ y, int rows)
{
    int r = blockIdx.x * 256 + threadIdx.x;
    if (r >= rows) return;
    const float4* xr = (const float4*)(x + (size_t)r * 16);
    float v[16];
    *(float4*)(v + 0)  = xr[0];
    *(float4*)(v + 4)  = xr[1];
    *(float4*)(v + 8)  = xr[2];
    *(float4*)(v + 12) = xr[3];
    float mu = 0.f;
    #pragma unroll
    for (int i = 0; i < 16; ++i) mu += v[i];
    mu *= (1.f / 16.f);
    float var = 0.f;
    #pragma unroll
    for (int i = 0; i < 16; ++i) { float d = v[i] - mu; var += d * d; }
    var *= (1.f / 16.f);
    float rs = rsqrtf(var + LN_EPS);
    float o[16];
    #pragma unroll
    for (int i = 0; i < 16; ++i) o[i] = (v[i] - mu) * rs * g[i] + b[i];
    float4* yr = (float4*)(y + (size_t)r * 16);
    yr[0] = *(float4*)(o + 0);
    yr[1] = *(float4*)(o + 4);
    yr[2] = *(float4*)(o + 8);
    yr[3] = *(float4*)(o + 12);
}

// ---------------------------------------------------------------------------
// LayerNorm over last dim F=64 (one wave per row)
// ---------------------------------------------------------------------------
__global__ void ln64_kernel(const float* __restrict__ x, const float* __restrict__ g,
                            const float* __restrict__ b, float* __restrict__ y, int rows)
{
    int gidx = blockIdx.x * 256 + threadIdx.x;
    int row  = gidx >> 6;
    int lane = gidx & 63;
    if (row >= rows) return;
    float v = x[(size_t)row * 64 + lane];
    float s = v;
    #pragma unroll
    for (int o = 32; o > 0; o >>= 1) s += __shfl_xor(s, o);
    float mu = s * (1.f / 64.f);
    float d = v - mu;
    float q = d * d;
    #pragma unroll
    for (int o = 32; o > 0; o >>= 1) q += __shfl_xor(q, o);
    float rs = rsqrtf(q * (1.f / 64.f) + LN_EPS);
    y[(size_t)row * 64 + lane] = d * rs * g[lane] + b[lane];
}

// ---------------------------------------------------------------------------
// Generic 5x5 conv, NHWC in, HWIO weights, 256 output channels.
// Block: 256 threads; tile = 8x8 pixels x 128 couts.
// LDS: input patch [12][12][CIN] (HWC, same as global) + weight slice
//      [CICH][128] staged per (dy,dx,chunk). CIN=64 -> 52KB LDS -> 3 blk/CU.
// Per thread: 8 pixels x 4 couts, inner loop vectorized over 4 input chans.
// ---------------------------------------------------------------------------
template<int CIN, int PAD>
__global__ __launch_bounds__(256)
void conv5x5_kernel(const float* __restrict__ in, size_t in_bstride,
                    const float* __restrict__ wt, const float* __restrict__ bias,
                    float* __restrict__ out,
                    int IH, int IW, int OH, int OW)
{
    constexpr int TILE = 8, PATCH = 12, COT = 128;
    constexpr int CICH = (CIN < 32) ? CIN : 32;
    constexpr int NCH  = CIN / CICH;

    __shared__ float sIn[PATCH * PATCH * CIN];
    __shared__ float sW[CICH * COT];

    const int tid    = threadIdx.x;
    const int tilesX = (OW + TILE - 1) / TILE;
    const int ox0 = (blockIdx.x % tilesX) * TILE;
    const int oy0 = (blockIdx.x / tilesX) * TILE;
    const int co0 = blockIdx.y * COT;
    const int n   = blockIdx.z;

    // ---- stage input patch (layout identical to global HWC => coalesced) ----
    const float* inN = in + (size_t)n * in_bstride;
    constexpr int NF4 = PATCH * PATCH * CIN / 4;
    for (int e4 = tid; e4 < NF4; e4 += 256) {
        int cq  = e4 % (CIN / 4);
        int pix = e4 / (CIN / 4);
        int iy = pix / PATCH, ix = pix % PATCH;
        int gy = oy0 - PAD + iy, gx = ox0 - PAD + ix;
        float4 v = make_float4(0.f, 0.f, 0.f, 0.f);
        if (gy >= 0 && gy < IH && gx >= 0 && gx < IW)
            v = *(const float4*)(inN + ((size_t)(gy * IW + gx)) * CIN + cq * 4);
        *(float4*)(sIn + e4 * 4) = v;
    }

    const int co_grp = tid & 31;   // couts co0 + co_grp*4 .. +3
    const int prow   = tid >> 5;   // output row within 8x8 tile

    float acc[8][4];
    if (bias) {
        float4 bv = *(const float4*)(bias + co0 + co_grp * 4);
        #pragma unroll
        for (int j = 0; j < 8; ++j) {
            acc[j][0] = bv.x; acc[j][1] = bv.y; acc[j][2] = bv.z; acc[j][3] = bv.w;
        }
    } else {
        #pragma unroll
        for (int j = 0; j < 8; ++j)
            for (int k = 0; k < 4; ++k) acc[j][k] = 0.f;
    }

    for (int s = 0; s < 25 * NCH; ++s) {
        const int ch  = s % NCH;
        const int dxy = s / NCH;
        const int dy = dxy / 5, dx = dxy % 5;
        __syncthreads();
        const float* wslice = wt + ((size_t)(dxy * CIN + ch * CICH)) * 256 + co0;
        for (int e4 = tid; e4 < CICH * COT / 4; e4 += 256) {
            int f = e4 * 4;
            int ci = f >> 7, cw = f & 127;
            *(float4*)(sW + f) = *(const float4*)(wslice + ci * 256 + cw);
        }
        __syncthreads();

        const int iy = prow + dy;
        #pragma unroll 2
        for (int ci0 = 0; ci0 < CICH; ci0 += 4) {
            float4 b0 = *(const float4*)(sW + (ci0 + 0) * COT + co_grp * 4);
            float4 b1 = *(const float4*)(sW + (ci0 + 1) * COT + co_grp * 4);
            float4 b2 = *(const float4*)(sW + (ci0 + 2) * COT + co_grp * 4);
            float4 b3 = *(const float4*)(sW + (ci0 + 3) * COT + co_grp * 4);
            #pragma unroll
            for (int j = 0; j < 8; ++j) {
                float4 a = *(const float4*)(sIn + ((size_t)(iy * PATCH + dx + j)) * CIN
                                            + ch * CICH + ci0);
                acc[j][0] = fmaf(a.x, b0.x, acc[j][0]);
                acc[j][0] = fmaf(a.y, b1.x, acc[j][0]);
                acc[j][0] = fmaf(a.z, b2.x, acc[j][0]);
                acc[j][0] = fmaf(a.w, b3.x, acc[j][0]);
                acc[j][1] = fmaf(a.x, b0.y, acc[j][1]);
                acc[j][1] = fmaf(a.y, b1.y, acc[j][1]);
                acc[j][1] = fmaf(a.z, b2.y, acc[j][1]);
                acc[j][1] = fmaf(a.w, b3.y, acc[j][1]);
                acc[j][2] = fmaf(a.x, b0.z, acc[j][2]);
                acc[j][2] = fmaf(a.y, b1.z, acc[j][2]);
                acc[j][2] = fmaf(a.z, b2.z, acc[j][2]);
                acc[j][2] = fmaf(a.w, b3.z, acc[j][2]);
                acc[j][3] = fmaf(a.x, b0.w, acc[j][3]);
                acc[j][3] = fmaf(a.y, b1.w, acc[j][3]);
                acc[j][3] = fmaf(a.z, b2.w, acc[j][3]);
                acc[j][3] = fmaf(a.w, b3.w, acc[j][3]);
            }
        }
    }

    int oy = oy0 + prow;
    if (oy < OH) {
        float* orow = out + (((size_t)n * OH + oy) * OW) * 256 + co0 + co_grp * 4;
        #pragma unroll
        for (int j = 0; j < 8; ++j) {
            if (ox0 + j < OW)
                *(float4*)(orow + (size_t)(ox0 + j) * 256) =
                    make_float4(acc[j][0], acc[j][1], acc[j][2], acc[j][3]);
        }
    }
}

// ---------------------------------------------------------------------------
// LSTM gate pointwise update. Gate layout along channel: [i|f|cg|o] x 64.
// ---------------------------------------------------------------------------
__device__ __forceinline__ float hsig(float x)
{
    return fminf(fmaxf(fmaf(x, 0.2f, 0.5f), 0.f), 1.f);
}

__device__ __forceinline__ void gate1(float i_, float f_, float cg_, float o_,
                                      float cp, float& cn, float& hn)
{
    float ii = hsig(i_), ff = hsig(f_), oo = hsig(o_);
    float cc = fmaf(ff, cp, ii * tanhf(cg_));
    cn = cc;
    hn = oo * tanhf(cc);
}

template<bool FIRST>
__global__ void gates_kernel(const float* __restrict__ xg,  // [B,P,256]
                             const float* __restrict__ ug,  // [B,P,256] (null if FIRST)
                             float* __restrict__ c,         // [B,P,64]
                             float* __restrict__ h,         // [B,P,64]
                             int total)                     // B*P*16
{
    int e = blockIdx.x * 256 + threadIdx.x;
    if (e >= total) return;
    int fq    = (e & 15) * 4;
    size_t bp = (size_t)(e >> 4);

    const float* xgp = xg + bp * 256 + fq;
    float4 gi = *(const float4*)(xgp);
    float4 gf = *(const float4*)(xgp + 64);
    float4 gc = *(const float4*)(xgp + 128);
    float4 go = *(const float4*)(xgp + 192);
    float4 cv = make_float4(0.f, 0.f, 0.f, 0.f);
    if (!FIRST) {
        const float* ugp = ug + bp * 256 + fq;
        float4 ui = *(const float4*)(ugp);
        float4 uf = *(const float4*)(ugp + 64);
        float4 uc = *(const float4*)(ugp + 128);
        float4 uo = *(const float4*)(ugp + 192);
        gi.x += ui.x; gi.y += ui.y; gi.z += ui.z; gi.w += ui.w;
        gf.x += uf.x; gf.y += uf.y; gf.z += uf.z; gf.w += uf.w;
        gc.x += uc.x; gc.y += uc.y; gc.z += uc.z; gc.w += uc.w;
        go.x += uo.x; go.y += uo.y; go.z += uo.z; go.w += uo.w;
        cv = *(const float4*)(c + bp * 64 + fq);
    }
    float4 cn, hn;
    gate1(gi.x, gf.x, gc.x, go.x, cv.x, cn.x, hn.x);
    gate1(gi.y, gf.y, gc.y, go.y, cv.y, cn.y, hn.y);
    gate1(gi.z, gf.z, gc.z, go.z, cv.z, cn.z, hn.z);
    gate1(gi.w, gf.w, gc.w, go.w, cv.w, cn.w, hn.w);
    *(float4*)(c + bp * 64 + fq) = cn;
    *(float4*)(h + bp * 64 + fq) = hn;
}

// ---------------------------------------------------------------------------
// Final: mean over 32x32 pixels, dot with dw[64], +db, *0.1. One block per b.
// ---------------------------------------------------------------------------
__global__ void pool_dot_kernel(const float* __restrict__ h, const float* __restrict__ dw,
                                const float* __restrict__ db, float* __restrict__ out)
{
    int b = blockIdx.x;
    __shared__ float sdw[64];
    if (threadIdx.x < 64) sdw[threadIdx.x] = dw[threadIdx.x];
    __syncthreads();
    float partial = 0.f;
    const float* hb = h + (size_t)b * 1024 * 64;
    for (int p = threadIdx.x; p < 1024; p += 256) {
        const float* hp = hb + (size_t)p * 64;
        #pragma unroll
        for (int f = 0; f < 64; f += 4) {
            float4 hv = *(const float4*)(hp + f);
            partial += hv.x * sdw[f] + hv.y * sdw[f + 1] + hv.z * sdw[f + 2] + hv.w * sdw[f + 3];
        }
    }
    #pragma unroll
    for (int o = 32; o > 0; o >>= 1) partial += __shfl_xor(partial, o);
    __shared__ float ws[4];
    if ((threadIdx.x & 63) == 0) ws[threadIdx.x >> 6] = partial;
    __syncthreads();
    if (threadIdx.x == 0) {
        float tot = ws[0] + ws[1] + ws[2] + ws[3];
        out[b] = (tot * (1.f / 1024.f) + db[0]) * 0.1f;
    }
}

// ---------------------------------------------------------------------------
// Orchestration. Fully time-fused pipeline: LSTM2 step t only needs LSTM1's
// step-t output, so one loop runs both layers -> workspace ~63 MB.
// ---------------------------------------------------------------------------
extern "C" void kernel_launch(void* const* d_in, const int* in_sizes, int n_in,
                              void* d_out, int out_size, void* d_ws, size_t ws_size,
                              hipStream_t stream)
{
    const float* x   = (const float*)d_in[0];
    const float* lg1 = (const float*)d_in[1];
    const float* lb1 = (const float*)d_in[2];
    const float* W1  = (const float*)d_in[3];
    const float* U1  = (const float*)d_in[4];
    const float* b1  = (const float*)d_in[5];
    const float* lg2 = (const float*)d_in[6];
    const float* lb2 = (const float*)d_in[7];
    const float* W2  = (const float*)d_in[8];
    const float* U2  = (const float*)d_in[9];
    const float* b2  = (const float*)d_in[10];
    const float* dw  = (const float*)d_in[11];
    const float* db  = (const float*)d_in[12];
    float* out = (float*)d_out;

    constexpr int B = 8, T = 16;
    constexpr int P1 = 36 * 36, P2 = 32 * 32;

    float* w = (float*)d_ws;
    size_t off = 0;
    float* xln = w + off; off += (size_t)B * T * 40 * 40 * 16;  // 3,276,800
    float* xg1 = w + off; off += (size_t)B * P1 * 256;          // 2,654,208
    float* ug1 = w + off; off += (size_t)B * P1 * 256;
    float* h1  = w + off; off += (size_t)B * P1 * 64;
    float* c1  = w + off; off += (size_t)B * P1 * 64;
    float* hln = w + off; off += (size_t)B * P1 * 64;
    float* xg2 = w + off; off += (size_t)B * P2 * 256;
    float* ug2 = w + off; off += (size_t)B * P2 * 256;
    float* h2  = w + off; off += (size_t)B * P2 * 64;
    float* c2  = w + off; off += (size_t)B * P2 * 64;
    // total: 15,818,752 floats = 63.3 MB (fits comfortably in d_ws)

    // LayerNorm1 over C=16: 8*16*40*40 = 204800 rows
    ln16_kernel<<<800, 256, 0, stream>>>(x, lg1, lb1, xln, 204800);

    for (int t = 0; t < T; ++t) {
        // input-conv for LSTM1, frames (b, t): batch stride T*40*40*16
        conv5x5_kernel<16, 0><<<dim3(25, 2, B), 256, 0, stream>>>(
            xln + (size_t)t * 40 * 40 * 16, (size_t)T * 40 * 40 * 16,
            W1, b1, xg1, 40, 40, 36, 36);
        if (t > 0)
            conv5x5_kernel<64, 2><<<dim3(25, 2, B), 256, 0, stream>>>(
                h1, (size_t)P1 * 64, U1, nullptr, ug1, 36, 36, 36, 36);
        if (t == 0)
            gates_kernel<true><<<648, 256, 0, stream>>>(xg1, nullptr, c1, h1, B * P1 * 16);
        else
            gates_kernel<false><<<648, 256, 0, stream>>>(xg1, ug1, c1, h1, B * P1 * 16);

        // LayerNorm2 over F=64 on h1: 8*1296 = 10368 rows -> 2592 blocks
        ln64_kernel<<<2592, 256, 0, stream>>>(h1, lg2, lb2, hln, B * P1);

        // input-conv for LSTM2 (VALID 36->32)
        conv5x5_kernel<64, 0><<<dim3(16, 2, B), 256, 0, stream>>>(
            hln, (size_t)P1 * 64, W2, b2, xg2, 36, 36, 32, 32);
        if (t > 0)
            conv5x5_kernel<64, 2><<<dim3(16, 2, B), 256, 0, stream>>>(
                h2, (size_t)P2 * 64, U2, nullptr, ug2, 32, 32, 32, 32);
        if (t == 0)
            gates_kernel<true><<<512, 256, 0, stream>>>(xg2, nullptr, c2, h2, B * P2 * 16);
        else
            gates_kernel<false><<<512, 256, 0, stream>>>(xg2, ug2, c2, h2, B * P2 * 16);
    }

    pool_dot_kernel<<<B, 256, 0, stream>>>(h2, dw, db, out);
}

// Round 3
// 1465.199 us; speedup vs baseline: 5.8281x; 5.8281x over previous
//
#include <hip/hip_runtime.h>
#include <hip/hip_bf16.h>
#include <cstddef>

#define LN_EPS 1e-3f

typedef short bf16x8 __attribute__((ext_vector_type(8)));
typedef float f32x4 __attribute__((ext_vector_type(4)));

__device__ __forceinline__ unsigned short f2bf(float f) {
    __hip_bfloat16 b = __float2bfloat16(f);
    unsigned short u;
    __builtin_memcpy(&u, &b, 2);
    return u;
}

__device__ __forceinline__ float hsig(float x) {
    return fminf(fmaxf(fmaf(x, 0.2f, 0.5f), 0.f), 1.f);
}

// ---------------------------------------------------------------------------
// LayerNorm over last dim C=16 (one thread per row of 16)
// ---------------------------------------------------------------------------
__global__ void ln16_kernel(const float* __restrict__ x, const float* __restrict__ g,
                            const float* __restrict__ b, float* __restrict__ y, int rows)
{
    int r = blockIdx.x * 256 + threadIdx.x;
    if (r >= rows) return;
    const float4* xr = (const float4*)(x + (size_t)r * 16);
    float v[16];
    *(float4*)(v + 0)  = xr[0];
    *(float4*)(v + 4)  = xr[1];
    *(float4*)(v + 8)  = xr[2];
    *(float4*)(v + 12) = xr[3];
    float mu = 0.f;
    #pragma unroll
    for (int i = 0; i < 16; ++i) mu += v[i];
    mu *= (1.f / 16.f);
    float var = 0.f;
    #pragma unroll
    for (int i = 0; i < 16; ++i) { float d = v[i] - mu; var += d * d; }
    var *= (1.f / 16.f);
    float rs = rsqrtf(var + LN_EPS);
    float o[16];
    #pragma unroll
    for (int i = 0; i < 16; ++i) o[i] = (v[i] - mu) * rs * g[i] + b[i];
    float4* yr = (float4*)(y + (size_t)r * 16);
    yr[0] = *(float4*)(o + 0);
    yr[1] = *(float4*)(o + 4);
    yr[2] = *(float4*)(o + 8);
    yr[3] = *(float4*)(o + 12);
}

// ---------------------------------------------------------------------------
// Weight prep: fp32 HWIO [K][256] -> bf16 pre-chunked [chunk][256 co][32 k],
// zero-padded for k >= K. Coalesced reads (lane = co).
// ---------------------------------------------------------------------------
__global__ void prep_w(const float* __restrict__ w, short* __restrict__ o, int K, int NC)
{
    int e = blockIdx.x * 256 + threadIdx.x;
    int tot = NC * 32 * 256;
    if (e >= tot) return;
    int co = e & 255;
    int k  = e >> 8;
    float v = (k < K) ? w[(size_t)k * 256 + co] : 0.f;
    int chunk = k >> 5, kk = k & 31;
    o[((size_t)chunk * 256 + co) * 32 + kk] = (short)f2bf(v);
}

// ---------------------------------------------------------------------------
// MFMA implicit-GEMM 5x5 conv core. Block: 128 flattened pixels x 64 couts,
// 4 waves (wave = 64px x 32co = 4 M-frags x 2 N-frags, 16x16x32 bf16 MFMA).
// Patch (fp32->bf16, XOR-swizzled) staged once; weights double-buffered.
// ---------------------------------------------------------------------------
#define SMEM_MAX 56320

template<int CIN, int PAD, int OW, int OH>
__device__ void conv_core(int lblk, const float* __restrict__ in, size_t in_bstride,
                          int IH, int IW, const short* __restrict__ wts,
                          const float* __restrict__ bias, float* __restrict__ out,
                          char* smem)
{
    constexpr int PW = OW + 4;
    constexpr int OHW = OW * OH;
    constexpr int NTIL = (OHW + 127) / 128;
    constexpr int K = 25 * CIN;
    constexpr int NC = (K + 31) / 32;
    constexpr int PRMAX = (CIN == 16) ? 10 : 9;   // extra zero row for K-pad taps
    constexpr int SH = (CIN == 64) ? 7 : 6;       // swizzle source bits
    constexpr int GPP = CIN / 8;                  // 16B-groups per pixel
    constexpr int PATCH_BYTES = PRMAX * PW * CIN * 2;

    const int tid  = threadIdx.x;
    const int tile = lblk % NTIL;
    const int q    = (lblk / NTIL) & 3;
    const int n    = lblk / (NTIL * 4);
    const int p0   = tile * 128;
    const int r0   = p0 / OW;
    const int co0  = q * 64;

    short* sw = (short*)(smem + PATCH_BYTES);     // [2][64][40 shorts=80B padded row]
    const float* inN = in + (size_t)n * in_bstride;

    // ---- stage input patch: fp32 global -> bf16 swizzled LDS (once) ----
    constexpr int TOTG = PRMAX * PW * GPP;
    for (int gg = tid; gg < TOTG; gg += 256) {
        int pix = gg / GPP;
        int cig = gg % GPP;
        int pr = pix / PW, pc = pix % PW;
        int gy = r0 - PAD + pr;
        int gx = pc - PAD;
        float v[8] = {0.f,0.f,0.f,0.f,0.f,0.f,0.f,0.f};
        bool ok = (gy >= 0) & (gy < IH) & (gx >= 0) & (gx < IW);
        if (CIN == 16 && pr == PRMAX - 1) ok = false;   // zero row for k>=400 pad
        if (ok) {
            const float* p = inN + ((size_t)gy * IW + gx) * CIN + cig * 8;
            float4 f0 = *(const float4*)p;
            float4 f1 = *(const float4*)(p + 4);
            v[0]=f0.x; v[1]=f0.y; v[2]=f0.z; v[3]=f0.w;
            v[4]=f1.x; v[5]=f1.y; v[6]=f1.z; v[7]=f1.w;
        }
        union { bf16x8 v8; unsigned short u[8]; } pk;
        #pragma unroll
        for (int i = 0; i < 8; ++i) pk.u[i] = f2bf(v[i]);
        int ad = (pix * CIN + cig * 8) * 2;
        ad ^= ((ad >> SH) & 7) << 4;               // bank-conflict swizzle
        *(bf16x8*)(smem + ad) = pk.v8;
    }

    // ---- stage weight chunk 0 (256 thr x 16B = 4KB = 64co x 64B) ----
    {
        const short* src = wts + ((size_t)co0 + (tid >> 2)) * 32 + (tid & 3) * 8;
        int4 w0 = *(const int4*)src;
        *(int4*)(sw + (tid >> 2) * 40 + (tid & 3) * 8) = w0;
    }
    __syncthreads();

    const int lane = tid & 63;
    const int wid  = tid >> 6;
    const int wm   = wid >> 1;                    // pixel half (64)
    const int wn   = wid & 1;                     // cout half (32)
    const int lr   = lane & 15;
    const int g    = lane >> 4;

    int base_m[4];
    #pragma unroll
    for (int m = 0; m < 4; ++m) {
        int px = p0 + wm * 64 + m * 16 + lr;
        int r = px / OW;
        int x = px - r * OW;
        base_m[m] = ((r - r0) * PW + x) * CIN * 2;
    }

    f32x4 acc[4][2];
    #pragma unroll
    for (int m = 0; m < 4; ++m)
        #pragma unroll
        for (int nn = 0; nn < 2; ++nn)
            acc[m][nn] = (f32x4){0.f, 0.f, 0.f, 0.f};

    // wave-uniform tap trackers (no per-chunk integer divide)
    int dy0 = 0, dx0 = 0;      // CIN64: tap=c>>1 ; CIN16: tap0=2c
    int dy1 = 0, dx1 = 1;      // CIN16: tap1=2c+1

    for (int c = 0; c < NC; ++c) {
        int4 wreg;
        const bool pf = (c + 1 < NC);
        if (pf) {   // issue next-chunk global load early (hides under MFMA)
            const short* src = wts + ((size_t)(c + 1) * 256 + co0 + (tid >> 2)) * 32
                             + (tid & 3) * 8;
            wreg = *(const int4*)src;
        }
        int off;
        if (CIN == 64) {
            off = (dy0 * PW + dx0) * 128 + ((c & 1) << 6) + (g << 4);
        } else {
            int U0 = (dy0 * PW + dx0) * 32;
            int U1 = (dy1 * PW + dx1) * 32;
            off = ((g & 2) ? U1 : U0) + ((g & 1) << 4);
        }
        bf16x8 a[4];
        #pragma unroll
        for (int m = 0; m < 4; ++m) {
            int ad = base_m[m] + off;
            ad ^= ((ad >> SH) & 7) << 4;
            a[m] = *(const bf16x8*)(smem + ad);
        }
        const short* swc = sw + (c & 1) * 2560;
        bf16x8 b0 = *(const bf16x8*)(swc + (wn * 32 + lr) * 40 + g * 8);
        bf16x8 b1 = *(const bf16x8*)(swc + (wn * 32 + 16 + lr) * 40 + g * 8);
        #pragma unroll
        for (int m = 0; m < 4; ++m) {
            acc[m][0] = __builtin_amdgcn_mfma_f32_16x16x32_bf16(a[m], b0, acc[m][0], 0, 0, 0);
            acc[m][1] = __builtin_amdgcn_mfma_f32_16x16x32_bf16(a[m], b1, acc[m][1], 0, 0, 0);
        }
        if (pf) {
            short* dst = sw + ((c + 1) & 1) * 2560 + (tid >> 2) * 40 + (tid & 3) * 8;
            *(int4*)dst = wreg;
        }
        __syncthreads();
        if (CIN == 64) {
            if (c & 1) { if (++dx0 == 5) { dx0 = 0; ++dy0; } }
        } else {
            dx0 += 2; if (dx0 >= 5) { dx0 -= 5; ++dy0; }
            dx1 += 2; if (dx1 >= 5) { dx1 -= 5; ++dy1; }
        }
    }

    // ---- epilogue: C/D layout col=lane&15, row=g*4+j ----
    #pragma unroll
    for (int nn = 0; nn < 2; ++nn) {
        int co = co0 + wn * 32 + nn * 16 + lr;
        float bv = bias ? bias[co] : 0.f;
        #pragma unroll
        for (int m = 0; m < 4; ++m) {
            int pxb = p0 + wm * 64 + m * 16 + g * 4;
            #pragma unroll
            for (int j = 0; j < 4; ++j) {
                int px = pxb + j;
                if (px < OHW)
                    out[((size_t)n * OHW + px) * 256 + co] = acc[m][nn][j] + bv;
            }
        }
    }
}

// Merged launch: conv1-in(t) + conv1-rec + conv2-rec (mutually independent)
__global__ __launch_bounds__(256) void fused3_kernel(
    const float* __restrict__ xln_t, const float* __restrict__ h1,
    const float* __restrict__ h2,
    const short* __restrict__ wb1, const short* __restrict__ ub1,
    const short* __restrict__ ub2,
    const float* __restrict__ b1,
    float* __restrict__ xg1, float* __restrict__ ug1, float* __restrict__ ug2,
    int n1, int n2)
{
    __shared__ __align__(16) char smem[SMEM_MAX];
    int bid = blockIdx.x;
    if (bid < n1) {
        conv_core<16, 0, 36, 36>(bid, xln_t, 409600, 40, 40, wb1, b1, xg1, smem);
    } else if (bid < n1 + n2) {
        conv_core<64, 2, 36, 36>(bid - n1, h1, 82944, 36, 36, ub1, nullptr, ug1, smem);
    } else {
        conv_core<64, 2, 32, 32>(bid - n1 - n2, h2, 65536, 32, 32, ub2, nullptr, ug2, smem);
    }
}

__global__ __launch_bounds__(256) void conv2in_kernel(
    const float* __restrict__ hln, const short* __restrict__ wb2,
    const float* __restrict__ b2, float* __restrict__ xg2)
{
    __shared__ __align__(16) char smem[SMEM_MAX];
    conv_core<64, 0, 32, 32>(blockIdx.x, hln, 82944, 36, 36, wb2, b2, xg2, smem);
}

// ---------------------------------------------------------------------------
// Fused LSTM gates (+ optional LayerNorm-64 of h). One wave per pixel.
// ---------------------------------------------------------------------------
template<bool FIRST, bool DOLN>
__global__ void gates_ln_kernel(const float* __restrict__ xg, const float* __restrict__ ug,
                                float* __restrict__ c, float* __restrict__ h,
                                float* __restrict__ hln,
                                const float* __restrict__ lg, const float* __restrict__ lb,
                                int total)
{
    int idx = blockIdx.x * 256 + threadIdx.x;
    int w = idx >> 6;
    int f = idx & 63;
    if (w >= total) return;
    size_t b256 = (size_t)w * 256;
    size_t b64  = (size_t)w * 64;
    float gi = xg[b256 + f];
    float gf = xg[b256 + 64 + f];
    float gc = xg[b256 + 128 + f];
    float go = xg[b256 + 192 + f];
    float cp = 0.f;
    if (!FIRST) {
        gi += ug[b256 + f];
        gf += ug[b256 + 64 + f];
        gc += ug[b256 + 128 + f];
        go += ug[b256 + 192 + f];
        cp = c[b64 + f];
    }
    float ii = hsig(gi), ff = hsig(gf), oo = hsig(go);
    float cn = fmaf(ff, cp, ii * tanhf(gc));
    float hv = oo * tanhf(cn);
    c[b64 + f] = cn;
    h[b64 + f] = hv;
    if (DOLN) {
        float s = hv;
        #pragma unroll
        for (int o = 32; o > 0; o >>= 1) s += __shfl_xor(s, o);
        float mu = s * (1.f / 64.f);
        float d = hv - mu;
        float qv = d * d;
        #pragma unroll
        for (int o = 32; o > 0; o >>= 1) qv += __shfl_xor(qv, o);
        float rs = rsqrtf(qv * (1.f / 64.f) + LN_EPS);
        hln[b64 + f] = d * rs * lg[f] + lb[f];
    }
}

// ---------------------------------------------------------------------------
// Final: mean over 32x32 pixels, dot dw[64], +db, *0.1
// ---------------------------------------------------------------------------
__global__ void pool_dot_kernel(const float* __restrict__ h, const float* __restrict__ dw,
                                const float* __restrict__ db, float* __restrict__ out)
{
    int b = blockIdx.x;
    __shared__ float sdw[64];
    if (threadIdx.x < 64) sdw[threadIdx.x] = dw[threadIdx.x];
    __syncthreads();
    float partial = 0.f;
    const float* hb = h + (size_t)b * 1024 * 64;
    for (int p = threadIdx.x; p < 1024; p += 256) {
        const float* hp = hb + (size_t)p * 64;
        #pragma unroll
        for (int f = 0; f < 64; f += 4) {
            float4 hv = *(const float4*)(hp + f);
            partial += hv.x * sdw[f] + hv.y * sdw[f + 1] + hv.z * sdw[f + 2] + hv.w * sdw[f + 3];
        }
    }
    #pragma unroll
    for (int o = 32; o > 0; o >>= 1) partial += __shfl_xor(partial, o);
    __shared__ float ws[4];
    if ((threadIdx.x & 63) == 0) ws[threadIdx.x >> 6] = partial;
    __syncthreads();
    if (threadIdx.x == 0) {
        float tot = ws[0] + ws[1] + ws[2] + ws[3];
        out[b] = (tot * (1.f / 1024.f) + db[0]) * 0.1f;
    }
}

// ---------------------------------------------------------------------------
// Orchestration
// ---------------------------------------------------------------------------
extern "C" void kernel_launch(void* const* d_in, const int* in_sizes, int n_in,
                              void* d_out, int out_size, void* d_ws, size_t ws_size,
                              hipStream_t stream)
{
    const float* x   = (const float*)d_in[0];
    const float* lg1 = (const float*)d_in[1];
    const float* lb1 = (const float*)d_in[2];
    const float* W1  = (const float*)d_in[3];
    const float* U1  = (const float*)d_in[4];
    const float* b1  = (const float*)d_in[5];
    const float* lg2 = (const float*)d_in[6];
    const float* lb2 = (const float*)d_in[7];
    const float* W2  = (const float*)d_in[8];
    const float* U2  = (const float*)d_in[9];
    const float* b2  = (const float*)d_in[10];
    const float* dw  = (const float*)d_in[11];
    const float* db  = (const float*)d_in[12];
    float* out = (float*)d_out;

    constexpr int B = 8, T = 16;
    constexpr int P1 = 36 * 36, P2 = 32 * 32;

    float* w = (float*)d_ws;
    size_t off = 0;
    float* xln = w + off; off += (size_t)B * T * 40 * 40 * 16;  // 3,276,800
    float* xg1 = w + off; off += (size_t)B * P1 * 256;          // xg2 aliases this
    float* ug1 = w + off; off += (size_t)B * P1 * 256;
    float* ug2 = w + off; off += (size_t)B * P2 * 256;
    float* h1  = w + off; off += (size_t)B * P1 * 64;
    float* c1  = w + off; off += (size_t)B * P1 * 64;
    float* hln = w + off; off += (size_t)B * P1 * 64;
    float* h2  = w + off; off += (size_t)B * P2 * 64;
    float* c2  = w + off; off += (size_t)B * P2 * 64;
    short* wb1 = (short*)(w + off); off += (size_t)13 * 8192 / 2;
    short* ub1 = (short*)(w + off); off += (size_t)50 * 8192 / 2;
    short* wb2 = (short*)(w + off); off += (size_t)50 * 8192 / 2;
    short* ub2 = (short*)(w + off); off += (size_t)50 * 8192 / 2;
    float* xg2 = xg1;   // safe alias: xg1's last read precedes xg2's write each step

    // one-time transforms
    ln16_kernel<<<800, 256, 0, stream>>>(x, lg1, lb1, xln, 204800);
    prep_w<<<416, 256, 0, stream>>>(W1, wb1, 400, 13);
    prep_w<<<1600, 256, 0, stream>>>(U1, ub1, 1600, 50);
    prep_w<<<1600, 256, 0, stream>>>(W2, wb2, 1600, 50);
    prep_w<<<1600, 256, 0, stream>>>(U2, ub2, 1600, 50);

    constexpr int N1 = 11 * 4 * B;   // 352 conv1-in blocks
    constexpr int N2 = 11 * 4 * B;   // 352 conv1-rec blocks
    constexpr int N3 = 8 * 4 * B;    // 256 conv2-rec blocks

    for (int t = 0; t < T; ++t) {
        int n2 = (t > 0) ? N2 : 0;
        int n3 = (t > 0) ? N3 : 0;
        fused3_kernel<<<N1 + n2 + n3, 256, 0, stream>>>(
            xln + (size_t)t * 25600, h1, h2, wb1, ub1, ub2, b1, xg1, ug1, ug2, N1, n2);

        if (t == 0)
            gates_ln_kernel<true, true><<<2592, 256, 0, stream>>>(
                xg1, nullptr, c1, h1, hln, lg2, lb2, B * P1);
        else
            gates_ln_kernel<false, true><<<2592, 256, 0, stream>>>(
                xg1, ug1, c1, h1, hln, lg2, lb2, B * P1);

        conv2in_kernel<<<8 * 4 * B, 256, 0, stream>>>(hln, wb2, b2, xg2);

        if (t == 0)
            gates_ln_kernel<true, false><<<2048, 256, 0, stream>>>(
                xg2, nullptr, c2, h2, nullptr, nullptr, nullptr, B * P2);
        else
            gates_ln_kernel<false, false><<<2048, 256, 0, stream>>>(
                xg2, ug2, c2, h2, nullptr, nullptr, nullptr, B * P2);
    }

    pool_dot_kernel<<<B, 256, 0, stream>>>(h2, dw, db, out);
}

// Round 4
// 1154.618 us; speedup vs baseline: 7.3958x; 1.2690x over previous
//
#include <hip/hip_runtime.h>
#include <hip/hip_bf16.h>
#include <cstddef>

#define LN_EPS 1e-3f

typedef short bf16x8 __attribute__((ext_vector_type(8)));
typedef float f32x4 __attribute__((ext_vector_type(4)));

__device__ __forceinline__ unsigned short f2bf(float f) {
    __hip_bfloat16 b = __float2bfloat16(f);
    unsigned short u;
    __builtin_memcpy(&u, &b, 2);
    return u;
}

__device__ __forceinline__ float hsig(float x) {
    return fminf(fmaxf(fmaf(x, 0.2f, 0.5f), 0.f), 1.f);
}

// ---------------------------------------------------------------------------
// LayerNorm over last dim C=16 (one thread per row of 16)
// ---------------------------------------------------------------------------
__global__ void ln16_kernel(const float* __restrict__ x, const float* __restrict__ g,
                            const float* __restrict__ b, float* __restrict__ y, int rows)
{
    int r = blockIdx.x * 256 + threadIdx.x;
    if (r >= rows) return;
    const float4* xr = (const float4*)(x + (size_t)r * 16);
    float v[16];
    *(float4*)(v + 0)  = xr[0];
    *(float4*)(v + 4)  = xr[1];
    *(float4*)(v + 8)  = xr[2];
    *(float4*)(v + 12) = xr[3];
    float mu = 0.f;
    #pragma unroll
    for (int i = 0; i < 16; ++i) mu += v[i];
    mu *= (1.f / 16.f);
    float var = 0.f;
    #pragma unroll
    for (int i = 0; i < 16; ++i) { float d = v[i] - mu; var += d * d; }
    var *= (1.f / 16.f);
    float rs = rsqrtf(var + LN_EPS);
    float o[16];
    #pragma unroll
    for (int i = 0; i < 16; ++i) o[i] = (v[i] - mu) * rs * g[i] + b[i];
    float4* yr = (float4*)(y + (size_t)r * 16);
    yr[0] = *(float4*)(o + 0);
    yr[1] = *(float4*)(o + 4);
    yr[2] = *(float4*)(o + 8);
    yr[3] = *(float4*)(o + 12);
}

// ---------------------------------------------------------------------------
// Weight prep: fp32 HWIO [K][256] -> bf16 pre-chunked [chunk][256 co][32 k],
// zero-padded for k >= K.
// ---------------------------------------------------------------------------
__global__ void prep_w(const float* __restrict__ w, short* __restrict__ o, int K, int NC)
{
    int e = blockIdx.x * 256 + threadIdx.x;
    int tot = NC * 32 * 256;
    if (e >= tot) return;
    int co = e & 255;
    int k  = e >> 8;
    float v = (k < K) ? w[(size_t)k * 256 + co] : 0.f;
    int chunk = k >> 5, kk = k & 31;
    o[((size_t)chunk * 256 + co) * 32 + kk] = (short)f2bf(v);
}

// ---------------------------------------------------------------------------
// MFMA implicit-GEMM 5x5 conv core. Block: 128 flattened pixels x 64 couts,
// 4 waves (wave = 64px x 32co = 4 M-frags x 2 N-frags, 16x16x32 bf16 MFMA).
// Patch (bf16, XOR-swizzled) staged once in LDS; B-fragments loaded DIRECTLY
// global->reg (layout [chunk][co][32k] == B-frag layout; 1KB coalesced/wave)
// with 1-chunk register prefetch. NO barriers in the K-loop.
// [C0,C1) = chunk range (K-split); PR0/PRN = staged patch-row window.
// ---------------------------------------------------------------------------
template<int CIN, int PAD, int OW, int OH, int C0, int C1, int PR0, int PRN>
__device__ void conv_core(int lblk, const float* __restrict__ in, size_t in_bstride,
                          int IH, int IW, const short* __restrict__ wts,
                          const float* __restrict__ bias, float* __restrict__ out,
                          char* smem)
{
    constexpr int PW  = OW + 4;
    constexpr int OHW = OW * OH;
    constexpr int NTIL = (OHW + 127) / 128;
    constexpr int SH  = (CIN == 64) ? 7 : 6;      // swizzle source bits
    constexpr int GPP = CIN / 8;                  // 16B-groups per pixel

    const int tid  = threadIdx.x;
    const int tile = lblk % NTIL;
    const int q    = (lblk / NTIL) & 3;
    const int n    = lblk / (NTIL * 4);
    const int p0   = tile * 128;
    const int r0   = p0 / OW;
    const int co0  = q * 64;

    const float* inN = in + (size_t)n * in_bstride;

    // ---- stage input patch rows [PR0, PR0+PRN): fp32 -> bf16 swizzled LDS ----
    constexpr int TOTG = PRN * PW * GPP;
    for (int gg = tid; gg < TOTG; gg += 256) {
        int pix = gg / GPP;
        int cig = gg % GPP;
        int pr = pix / PW, pc = pix % PW;
        int gy = r0 - PAD + PR0 + pr;
        int gx = pc - PAD;
        float v[8] = {0.f,0.f,0.f,0.f,0.f,0.f,0.f,0.f};
        bool ok = (gy >= 0) & (gy < IH) & (gx >= 0) & (gx < IW);
        if (CIN == 16 && pr == PRN - 1) ok = false;   // zero row for K-pad tap 25
        if (ok) {
            const float* p = inN + ((size_t)gy * IW + gx) * CIN + cig * 8;
            float4 f0 = *(const float4*)p;
            float4 f1 = *(const float4*)(p + 4);
            v[0]=f0.x; v[1]=f0.y; v[2]=f0.z; v[3]=f0.w;
            v[4]=f1.x; v[5]=f1.y; v[6]=f1.z; v[7]=f1.w;
        }
        union { bf16x8 v8; unsigned short u[8]; } pk;
        #pragma unroll
        for (int i = 0; i < 8; ++i) pk.u[i] = f2bf(v[i]);
        int ad = (pix * CIN + cig * 8) * 2;
        ad ^= ((ad >> SH) & 7) << 4;               // bank-conflict swizzle
        *(bf16x8*)(smem + ad) = pk.v8;
    }
    __syncthreads();   // the ONLY barrier: patch is read-only from here on

    const int lane = tid & 63;
    const int wid  = tid >> 6;
    const int wm   = wid >> 1;                    // pixel half (64)
    const int wn   = wid & 1;                     // cout half (32)
    const int lr   = lane & 15;
    const int g    = lane >> 4;

    int base_m[4];
    #pragma unroll
    for (int m = 0; m < 4; ++m) {
        int px = p0 + wm * 64 + m * 16 + lr;
        int r = px / OW;
        int x = px - r * OW;
        base_m[m] = ((r - r0 - PR0) * PW + x) * CIN * 2;
    }

    f32x4 acc[4][2];
    #pragma unroll
    for (int m = 0; m < 4; ++m)
        #pragma unroll
        for (int nn = 0; nn < 2; ++nn)
            acc[m][nn] = (f32x4){0.f, 0.f, 0.f, 0.f};

    // wave-uniform tap trackers (compile-time init from C0)
    int dy0, dx0, dy1, dx1;
    if (CIN == 64) {
        constexpr int tap = C0 >> 1;
        dy0 = tap / 5; dx0 = tap % 5; dy1 = 0; dx1 = 0;
    } else {
        constexpr int t0 = 2 * C0, t1 = 2 * C0 + 1;
        dy0 = t0 / 5; dx0 = t0 % 5; dy1 = t1 / 5; dx1 = t1 % 5;
    }

    // B-frag lane pointer: [chunk][co][32k]; wave's 64 lanes = 1KB contiguous
    const short* wlp = wts + ((size_t)C0 * 256 + co0 + wn * 32 + lr) * 32 + g * 8;
    bf16x8 bc0 = *(const bf16x8*)wlp;
    bf16x8 bc1 = *(const bf16x8*)(wlp + 512);     // +16 co

    for (int c = C0; c < C1; ++c) {
        bf16x8 bn0, bn1;
        const bool pf = (c + 1 < C1);
        if (pf) {   // register prefetch of next chunk's B-frags (L2-hot)
            const short* wnx = wlp + (size_t)(c + 1 - C0) * 8192;
            bn0 = *(const bf16x8*)wnx;
            bn1 = *(const bf16x8*)(wnx + 512);
        }
        int off;
        if (CIN == 64) {
            off = (dy0 * PW + dx0) * 128 + ((c & 1) << 6) + (g << 4);
        } else {
            int U0 = (dy0 * PW + dx0) * 32;
            int U1 = (dy1 * PW + dx1) * 32;
            off = ((g & 2) ? U1 : U0) + ((g & 1) << 4);
        }
        bf16x8 a[4];
        #pragma unroll
        for (int m = 0; m < 4; ++m) {
            int ad = base_m[m] + off;
            ad ^= ((ad >> SH) & 7) << 4;
            a[m] = *(const bf16x8*)(smem + ad);
        }
        #pragma unroll
        for (int m = 0; m < 4; ++m) {
            acc[m][0] = __builtin_amdgcn_mfma_f32_16x16x32_bf16(a[m], bc0, acc[m][0], 0, 0, 0);
            acc[m][1] = __builtin_amdgcn_mfma_f32_16x16x32_bf16(a[m], bc1, acc[m][1], 0, 0, 0);
        }
        if (pf) { bc0 = bn0; bc1 = bn1; }
        if (CIN == 64) {
            if (c & 1) { if (++dx0 == 5) { dx0 = 0; ++dy0; } }
        } else {
            dx0 += 2; if (dx0 >= 5) { dx0 -= 5; ++dy0; }
            dx1 += 2; if (dx1 >= 5) { dx1 -= 5; ++dy1; }
        }
    }

    // ---- epilogue: C/D layout col=lane&15, row=g*4+j ----
    #pragma unroll
    for (int nn = 0; nn < 2; ++nn) {
        int co = co0 + wn * 32 + nn * 16 + lr;
        float bv = bias ? bias[co] : 0.f;
        #pragma unroll
        for (int m = 0; m < 4; ++m) {
            int pxb = p0 + wm * 64 + m * 16 + g * 4;
            #pragma unroll
            for (int j = 0; j < 4; ++j) {
                int px = pxb + j;
                if (px < OHW)
                    out[((size_t)n * OHW + px) * 256 + co] = acc[m][nn][j] + bv;
            }
        }
    }
}

// Merged launch: conv1-in(t) + conv1-rec + conv2-rec (mutually independent)
__global__ __launch_bounds__(256, 3) void fused3_kernel(
    const float* __restrict__ xln_t, const float* __restrict__ h1,
    const float* __restrict__ h2,
    const short* __restrict__ wb1, const short* __restrict__ ub1,
    const short* __restrict__ ub2,
    const float* __restrict__ b1,
    float* __restrict__ xg1, float* __restrict__ ug1, float* __restrict__ ug2,
    int n1, int n2)
{
    __shared__ __align__(16) char smem[46080];   // conv1-rec patch: 9*40*64*2
    int bid = blockIdx.x;
    if (bid < n1) {
        conv_core<16, 0, 36, 36, 0, 13, 0, 10>(bid, xln_t, 409600, 40, 40, wb1, b1, xg1, smem);
    } else if (bid < n1 + n2) {
        conv_core<64, 2, 36, 36, 0, 50, 0, 9>(bid - n1, h1, 82944, 36, 36, ub1, nullptr, ug1, smem);
    } else {
        conv_core<64, 2, 32, 32, 0, 50, 0, 8>(bid - n1 - n2, h2, 65536, 32, 32, ub2, nullptr, ug2, smem);
    }
}

// conv2-in, K-split x2 (chunks 0-24 / 25-49), row-windowed 6-row patches.
__global__ __launch_bounds__(256, 4) void conv2in_kernel(
    const float* __restrict__ hln, const short* __restrict__ wb2,
    const float* __restrict__ b2, float* __restrict__ xg2a, float* __restrict__ xg2b)
{
    __shared__ __align__(16) char smem[27648];   // 6*36*64*2
    int bid = blockIdx.x;
    if (bid < 256)
        conv_core<64, 0, 32, 32,  0, 25, 0, 6>(bid,       hln, 82944, 36, 36, wb2, b2,      xg2a, smem);
    else
        conv_core<64, 0, 32, 32, 25, 50, 2, 6>(bid - 256, hln, 82944, 36, 36, wb2, nullptr, xg2b, smem);
}

// ---------------------------------------------------------------------------
// Fused LSTM gates (+ optional LayerNorm-64 of h). One lane per (pixel, f).
// ---------------------------------------------------------------------------
template<bool HAS_UG, bool HAS_XGB, bool DOLN>
__global__ void gates_ln_kernel(const float* __restrict__ xga, const float* __restrict__ xgb,
                                const float* __restrict__ ug,
                                float* __restrict__ c, float* __restrict__ h,
                                float* __restrict__ hln,
                                const float* __restrict__ lg, const float* __restrict__ lb,
                                int total)
{
    int idx = blockIdx.x * 256 + threadIdx.x;
    int w = idx >> 6;
    int f = idx & 63;
    if (w >= total) return;
    size_t b256 = (size_t)w * 256;
    size_t b64  = (size_t)w * 64;
    float gi = xga[b256 + f];
    float gf = xga[b256 + 64 + f];
    float gc = xga[b256 + 128 + f];
    float go = xga[b256 + 192 + f];
    if (HAS_XGB) {
        gi += xgb[b256 + f];
        gf += xgb[b256 + 64 + f];
        gc += xgb[b256 + 128 + f];
        go += xgb[b256 + 192 + f];
    }
    float cp = 0.f;
    if (HAS_UG) {
        gi += ug[b256 + f];
        gf += ug[b256 + 64 + f];
        gc += ug[b256 + 128 + f];
        go += ug[b256 + 192 + f];
        cp = c[b64 + f];
    }
    float ii = hsig(gi), ff = hsig(gf), oo = hsig(go);
    float cn = fmaf(ff, cp, ii * tanhf(gc));
    float hv = oo * tanhf(cn);
    c[b64 + f] = cn;
    h[b64 + f] = hv;
    if (DOLN) {
        float s = hv;
        #pragma unroll
        for (int o = 32; o > 0; o >>= 1) s += __shfl_xor(s, o);
        float mu = s * (1.f / 64.f);
        float d = hv - mu;
        float qv = d * d;
        #pragma unroll
        for (int o = 32; o > 0; o >>= 1) qv += __shfl_xor(qv, o);
        float rs = rsqrtf(qv * (1.f / 64.f) + LN_EPS);
        hln[b64 + f] = d * rs * lg[f] + lb[f];
    }
}

// ---------------------------------------------------------------------------
// Final: mean over 32x32 pixels, dot dw[64], +db, *0.1
// ---------------------------------------------------------------------------
__global__ void pool_dot_kernel(const float* __restrict__ h, const float* __restrict__ dw,
                                const float* __restrict__ db, float* __restrict__ out)
{
    int b = blockIdx.x;
    __shared__ float sdw[64];
    if (threadIdx.x < 64) sdw[threadIdx.x] = dw[threadIdx.x];
    __syncthreads();
    float partial = 0.f;
    const float* hb = h + (size_t)b * 1024 * 64;
    for (int p = threadIdx.x; p < 1024; p += 256) {
        const float* hp = hb + (size_t)p * 64;
        #pragma unroll
        for (int f = 0; f < 64; f += 4) {
            float4 hv = *(const float4*)(hp + f);
            partial += hv.x * sdw[f] + hv.y * sdw[f + 1] + hv.z * sdw[f + 2] + hv.w * sdw[f + 3];
        }
    }
    #pragma unroll
    for (int o = 32; o > 0; o >>= 1) partial += __shfl_xor(partial, o);
    __shared__ float ws[4];
    if ((threadIdx.x & 63) == 0) ws[threadIdx.x >> 6] = partial;
    __syncthreads();
    if (threadIdx.x == 0) {
        float tot = ws[0] + ws[1] + ws[2] + ws[3];
        out[b] = (tot * (1.f / 1024.f) + db[0]) * 0.1f;
    }
}

// ---------------------------------------------------------------------------
// Orchestration
// ---------------------------------------------------------------------------
extern "C" void kernel_launch(void* const* d_in, const int* in_sizes, int n_in,
                              void* d_out, int out_size, void* d_ws, size_t ws_size,
                              hipStream_t stream)
{
    const float* x   = (const float*)d_in[0];
    const float* lg1 = (const float*)d_in[1];
    const float* lb1 = (const float*)d_in[2];
    const float* W1  = (const float*)d_in[3];
    const float* U1  = (const float*)d_in[4];
    const float* b1  = (const float*)d_in[5];
    const float* lg2 = (const float*)d_in[6];
    const float* lb2 = (const float*)d_in[7];
    const float* W2  = (const float*)d_in[8];
    const float* U2  = (const float*)d_in[9];
    const float* b2  = (const float*)d_in[10];
    const float* dw  = (const float*)d_in[11];
    const float* db  = (const float*)d_in[12];
    float* out = (float*)d_out;

    constexpr int B = 8, T = 16;
    constexpr int P1 = 36 * 36, P2 = 32 * 32;

    float* w = (float*)d_ws;
    size_t off = 0;
    float* xln = w + off; off += (size_t)B * T * 40 * 40 * 16;  // 3,276,800
    float* xg1 = w + off; off += (size_t)B * P1 * 256;          // xg2a aliases this
    float* ug1 = w + off; off += (size_t)B * P1 * 256;          // xg2b aliases this
    float* ug2 = w + off; off += (size_t)B * P2 * 256;
    float* h1  = w + off; off += (size_t)B * P1 * 64;
    float* c1  = w + off; off += (size_t)B * P1 * 64;
    float* hln = w + off; off += (size_t)B * P1 * 64;
    float* h2  = w + off; off += (size_t)B * P2 * 64;
    float* c2  = w + off; off += (size_t)B * P2 * 64;
    short* wb1 = (short*)(w + off); off += (size_t)13 * 8192 / 2;
    short* ub1 = (short*)(w + off); off += (size_t)50 * 8192 / 2;
    short* wb2 = (short*)(w + off); off += (size_t)50 * 8192 / 2;
    short* ub2 = (short*)(w + off); off += (size_t)50 * 8192 / 2;
    // Aliases (lifetimes disjoint within a step; stream-ordered):
    //   xg2a lives conv2in(t)->gates2(t); xg1 lives fused3(t)->gates1(t). OK.
    //   xg2b lives conv2in(t)->gates2(t); ug1 lives fused3(t)->gates1(t),
    //   next write by fused3(t+1) AFTER gates2(t). OK.
    float* xg2a = xg1;
    float* xg2b = ug1;

    // one-time transforms
    ln16_kernel<<<800, 256, 0, stream>>>(x, lg1, lb1, xln, 204800);
    prep_w<<<416, 256, 0, stream>>>(W1, wb1, 400, 13);
    prep_w<<<1600, 256, 0, stream>>>(U1, ub1, 1600, 50);
    prep_w<<<1600, 256, 0, stream>>>(W2, wb2, 1600, 50);
    prep_w<<<1600, 256, 0, stream>>>(U2, ub2, 1600, 50);

    constexpr int N1 = 11 * 4 * B;   // 352 conv1-in blocks
    constexpr int N2 = 11 * 4 * B;   // 352 conv1-rec blocks
    constexpr int N3 = 8 * 4 * B;    // 256 conv2-rec blocks

    for (int t = 0; t < T; ++t) {
        int n2 = (t > 0) ? N2 : 0;
        int n3 = (t > 0) ? N3 : 0;
        fused3_kernel<<<N1 + n2 + n3, 256, 0, stream>>>(
            xln + (size_t)t * 25600, h1, h2, wb1, ub1, ub2, b1, xg1, ug1, ug2, N1, n2);

        if (t == 0)
            gates_ln_kernel<false, false, true><<<2592, 256, 0, stream>>>(
                xg1, nullptr, nullptr, c1, h1, hln, lg2, lb2, B * P1);
        else
            gates_ln_kernel<true, false, true><<<2592, 256, 0, stream>>>(
                xg1, nullptr, ug1, c1, h1, hln, lg2, lb2, B * P1);

        conv2in_kernel<<<512, 256, 0, stream>>>(hln, wb2, b2, xg2a, xg2b);

        if (t == 0)
            gates_ln_kernel<false, true, false><<<2048, 256, 0, stream>>>(
                xg2a, xg2b, nullptr, c2, h2, nullptr, nullptr, nullptr, B * P2);
        else
            gates_ln_kernel<true, true, false><<<2048, 256, 0, stream>>>(
                xg2a, xg2b, ug2, c2, h2, nullptr, nullptr, nullptr, B * P2);
    }

    pool_dot_kernel<<<B, 256, 0, stream>>>(h2, dw, db, out);
}

// Round 5
// 956.746 us; speedup vs baseline: 8.9254x; 1.2068x over previous
//
#include <hip/hip_runtime.h>
#include <hip/hip_bf16.h>
#include <cstddef>

#define LN_EPS 1e-3f

typedef short bf16x8 __attribute__((ext_vector_type(8)));
typedef float f32x4 __attribute__((ext_vector_type(4)));

__device__ __forceinline__ unsigned short f2bf(float f) {
    __hip_bfloat16 b = __float2bfloat16(f);
    unsigned short u;
    __builtin_memcpy(&u, &b, 2);
    return u;
}

__device__ __forceinline__ float hsig(float x) {
    return fminf(fmaxf(fmaf(x, 0.2f, 0.5f), 0.f), 1.f);
}

// ---------------------------------------------------------------------------
// LayerNorm over last dim C=16 (one thread per row of 16)
// ---------------------------------------------------------------------------
__global__ void ln16_kernel(const float* __restrict__ x, const float* __restrict__ g,
                            const float* __restrict__ b, float* __restrict__ y, int rows)
{
    int r = blockIdx.x * 256 + threadIdx.x;
    if (r >= rows) return;
    const float4* xr = (const float4*)(x + (size_t)r * 16);
    float v[16];
    *(float4*)(v + 0)  = xr[0];
    *(float4*)(v + 4)  = xr[1];
    *(float4*)(v + 8)  = xr[2];
    *(float4*)(v + 12) = xr[3];
    float mu = 0.f;
    #pragma unroll
    for (int i = 0; i < 16; ++i) mu += v[i];
    mu *= (1.f / 16.f);
    float var = 0.f;
    #pragma unroll
    for (int i = 0; i < 16; ++i) { float d = v[i] - mu; var += d * d; }
    var *= (1.f / 16.f);
    float rs = rsqrtf(var + LN_EPS);
    float o[16];
    #pragma unroll
    for (int i = 0; i < 16; ++i) o[i] = (v[i] - mu) * rs * g[i] + b[i];
    float4* yr = (float4*)(y + (size_t)r * 16);
    yr[0] = *(float4*)(o + 0);
    yr[1] = *(float4*)(o + 4);
    yr[2] = *(float4*)(o + 8);
    yr[3] = *(float4*)(o + 12);
}

// ---------------------------------------------------------------------------
// LayerNorm over last dim F=64 (one wave per row)
// ---------------------------------------------------------------------------
__global__ void ln64_kernel(const float* __restrict__ x, const float* __restrict__ g,
                            const float* __restrict__ b, float* __restrict__ y, int rows)
{
    int gidx = blockIdx.x * 256 + threadIdx.x;
    int row  = gidx >> 6;
    int lane = gidx & 63;
    if (row >= rows) return;
    float v = x[(size_t)row * 64 + lane];
    float s = v;
    #pragma unroll
    for (int o = 32; o > 0; o >>= 1) s += __shfl_xor(s, o);
    float mu = s * (1.f / 64.f);
    float d = v - mu;
    float q = d * d;
    #pragma unroll
    for (int o = 32; o > 0; o >>= 1) q += __shfl_xor(q, o);
    float rs = rsqrtf(q * (1.f / 64.f) + LN_EPS);
    y[(size_t)row * 64 + lane] = d * rs * g[lane] + b[lane];
}

// ---------------------------------------------------------------------------
// Weight prep with GATE-INTERLEAVED cout permutation:
//   co' = q*64 + wn*32 + gate*8 + fl  maps from  co_orig = gate*64 + (q*16+wn*8+fl)
// so each 64-co' block holds complete {i,f,cg,o} sets for 16 f-channels.
// fp32 [K][256] -> bf16 [chunk][256 co'][32 k], zero-padded k >= K.
// ---------------------------------------------------------------------------
__global__ void prep_w_perm(const float* __restrict__ w, short* __restrict__ o, int K, int NC)
{
    int e = blockIdx.x * 256 + threadIdx.x;
    int tot = NC * 32 * 256;
    if (e >= tot) return;
    int cop = e & 255;
    int k   = e >> 8;
    int qq   = cop >> 6;
    int wn   = (cop >> 5) & 1;
    int gate = (cop >> 3) & 3;
    int fl   = cop & 7;
    int fg = qq * 16 + wn * 8 + fl;
    int co_orig = gate * 64 + fg;
    float v = (k < K) ? w[(size_t)k * 256 + co_orig] : 0.f;
    int chunk = k >> 5, kk = k & 31;
    o[((size_t)chunk * 256 + cop) * 32 + kk] = (short)f2bf(v);
}

// ---------------------------------------------------------------------------
// Stage input patch rows [0,PRN): fp32 global -> bf16 XOR-swizzled LDS
// ---------------------------------------------------------------------------
template<int CIN, int PAD, int PRN, int PW, bool ZEROROW>
__device__ __forceinline__ void stage_patch(char* smem, const float* __restrict__ inN,
                                            int IH, int IW, int r0)
{
    constexpr int GPP = CIN / 8;
    constexpr int SH  = (CIN == 64) ? 7 : 6;
    constexpr int TOTG = PRN * PW * GPP;
    const int tid = threadIdx.x;
    for (int gg = tid; gg < TOTG; gg += 256) {
        int pix = gg / GPP;
        int cig = gg % GPP;
        int pr = pix / PW, pc = pix % PW;
        int gy = r0 - PAD + pr;
        int gx = pc - PAD;
        float v[8] = {0.f,0.f,0.f,0.f,0.f,0.f,0.f,0.f};
        bool ok = (gy >= 0) & (gy < IH) & (gx >= 0) & (gx < IW);
        if (ZEROROW && pr == PRN - 1) ok = false;   // zero row for K-pad taps
        if (ok) {
            const float* p = inN + ((size_t)gy * IW + gx) * CIN + cig * 8;
            float4 f0 = *(const float4*)p;
            float4 f1 = *(const float4*)(p + 4);
            v[0]=f0.x; v[1]=f0.y; v[2]=f0.z; v[3]=f0.w;
            v[4]=f1.x; v[5]=f1.y; v[6]=f1.z; v[7]=f1.w;
        }
        union { bf16x8 v8; unsigned short u[8]; } pk;
        #pragma unroll
        for (int i = 0; i < 8; ++i) pk.u[i] = f2bf(v[i]);
        int ad = (pix * CIN + cig * 8) * 2;
        ad ^= ((ad >> SH) & 7) << 4;
        *(bf16x8*)(smem + ad) = pk.v8;
    }
}

// ---------------------------------------------------------------------------
// K-loop over NC chunks: A-frags from swizzled LDS patch, B-frags straight
// global->reg ([chunk][co'][32k] == B-frag layout) with 1-chunk prefetch.
// Accumulates into caller's acc. No barriers.
// ---------------------------------------------------------------------------
template<int CIN, int PW, int NC>
__device__ __forceinline__ void kloop(const char* smem, const short* __restrict__ wbase,
                                      int colane, int g, const int* base_m, f32x4 (&acc)[4][2])
{
    constexpr int SH = (CIN == 64) ? 7 : 6;
    const short* wlp = wbase + (size_t)colane * 32 + g * 8;
    bf16x8 bc0 = *(const bf16x8*)wlp;
    bf16x8 bc1 = *(const bf16x8*)(wlp + 512);     // +16 co'
    int dy0 = 0, dx0 = 0, dy1 = 0, dx1 = 1;
    for (int c = 0; c < NC; ++c) {
        bf16x8 bn0, bn1;
        const bool pf = (c + 1 < NC);
        if (pf) {
            const short* wnx = wlp + (size_t)(c + 1) * 8192;
            bn0 = *(const bf16x8*)wnx;
            bn1 = *(const bf16x8*)(wnx + 512);
        }
        int off;
        if (CIN == 64) {
            off = (dy0 * PW + dx0) * 128 + ((c & 1) << 6) + (g << 4);
        } else {
            int U0 = (dy0 * PW + dx0) * 32;
            int U1 = (dy1 * PW + dx1) * 32;
            off = ((g & 2) ? U1 : U0) + ((g & 1) << 4);
        }
        bf16x8 a[4];
        #pragma unroll
        for (int m = 0; m < 4; ++m) {
            int ad = base_m[m] + off;
            ad ^= ((ad >> SH) & 7) << 4;
            a[m] = *(const bf16x8*)(smem + ad);
        }
        #pragma unroll
        for (int m = 0; m < 4; ++m) {
            acc[m][0] = __builtin_amdgcn_mfma_f32_16x16x32_bf16(a[m], bc0, acc[m][0], 0, 0, 0);
            acc[m][1] = __builtin_amdgcn_mfma_f32_16x16x32_bf16(a[m], bc1, acc[m][1], 0, 0, 0);
        }
        if (pf) { bc0 = bn0; bc1 = bn1; }
        if (CIN == 64) {
            if (c & 1) { if (++dx0 == 5) { dx0 = 0; ++dy0; } }
        } else {
            dx0 += 2; if (dx0 >= 5) { dx0 -= 5; ++dy0; }
            dx1 += 2; if (dx1 >= 5) { dx1 -= 5; ++dy1; }
        }
    }
}

// ---------------------------------------------------------------------------
// One full ConvLSTM step for a (128px x 64co') tile with FUSED GATES:
//   phase1: W-conv chunks on in1 ; phase2 (if has_rec): U-conv chunks on hprev
//   epilogue: gate exchange via shfl_xor(8), c/h update in-place.
// Block = 256 thr (4 waves of 64px x 32co'); weights = [NC1 | NC2] chunks.
// ---------------------------------------------------------------------------
template<int CIN1, int PAD1, int NC1, int PRN1, bool ZR1,
         int NC2, int PRN2, int OW, int OH>
__device__ void lstm_step_core(int lblk, const float* __restrict__ in1, size_t in1_bstride,
                               int IH1, int IW1,
                               const float* __restrict__ hprev,
                               const short* __restrict__ wts, const float* __restrict__ bias,
                               float* __restrict__ cbuf, float* __restrict__ hbuf,
                               int has_rec, char* smem)
{
    constexpr int PW  = OW + 4;
    constexpr int OHW = OW * OH;
    constexpr int NTIL = (OHW + 127) / 128;
    constexpr bool FULL = (OHW % 128) == 0;

    const int tid  = threadIdx.x;
    const int tile = lblk % NTIL;
    const int q    = (lblk / NTIL) & 3;
    const int n    = lblk / (NTIL * 4);
    const int p0   = tile * 128;
    const int r0   = p0 / OW;
    const int co0  = q * 64;

    const int lane = tid & 63;
    const int wid  = tid >> 6;
    const int wm   = wid >> 1;
    const int wn   = wid & 1;
    const int lr   = lane & 15;
    const int g    = lane >> 4;

    int base1[4], base2[4];
    #pragma unroll
    for (int m = 0; m < 4; ++m) {
        int px = p0 + wm * 64 + m * 16 + lr;
        int r = px / OW;
        int x = px - r * OW;
        base1[m] = ((r - r0) * PW + x) * CIN1 * 2;
        base2[m] = ((r - r0) * PW + x) * 128;
    }

    f32x4 acc[4][2];
    #pragma unroll
    for (int m = 0; m < 4; ++m)
        #pragma unroll
        for (int nn = 0; nn < 2; ++nn)
            acc[m][nn] = (f32x4){0.f, 0.f, 0.f, 0.f};

    // ---- phase 1: W-conv ----
    stage_patch<CIN1, PAD1, PRN1, PW, ZR1>(smem, in1 + (size_t)n * in1_bstride, IH1, IW1, r0);
    __syncthreads();
    kloop<CIN1, PW, NC1>(smem, wts, co0 + wn * 32 + lr, g, base1, acc);

    // ---- phase 2: U-conv on previous h (restage same LDS) ----
    if (has_rec) {
        __syncthreads();
        stage_patch<64, 2, PRN2, PW, false>(smem, hprev + (size_t)n * OHW * 64, OH, OW, r0);
        __syncthreads();
        kloop<64, PW, NC2>(smem, wts + (size_t)NC1 * 8192, co0 + wn * 32 + lr, g, base2, acc);
    }

    // ---- fused gate epilogue ----
    // col co'' = wn*32 + nn*16 + lr -> gate = nn*2 + (lr>>3), f_local = lr&7.
    // lane lr holds {i,cg}; partner lr^8 holds {f,o} for the same (px set, f).
    const int fg = q * 16 + wn * 8 + (lr & 7);
    const bool low = (lr & 8) == 0;
    const float b0  = bias[(lr >> 3) * 64 + fg];         // gate 0/1 (i or f)
    const float b1v = bias[(2 + (lr >> 3)) * 64 + fg];   // gate 2/3 (cg or o)
    float* cN = cbuf + (size_t)n * OHW * 64;
    float* hN = hbuf + (size_t)n * OHW * 64;
    #pragma unroll
    for (int m = 0; m < 4; ++m) {
        int pxb = p0 + wm * 64 + m * 16 + g * 4;
        #pragma unroll
        for (int j = 0; j < 4; ++j) {
            int px = pxb + j;
            float a0 = acc[m][0][j] + b0;
            float a1 = acc[m][1][j] + b1v;
            float q0 = __shfl_xor(a0, 8);
            float q1 = __shfl_xor(a1, 8);
            float iv  = low ? a0 : q0;
            float fv  = low ? q0 : a0;
            float cgv = low ? a1 : q1;
            float ov  = low ? q1 : a1;
            bool valid = FULL || (px < OHW);
            int addr = px * 64 + fg;
            float cp = 0.f;
            if (has_rec && valid) cp = cN[addr];
            float cn = fmaf(hsig(fv), cp, hsig(iv) * tanhf(cgv));
            float hv = hsig(ov) * tanhf(cn);
            if (valid) {
                if (low) cN[addr] = cn;
                else     hN[addr] = hv;
            }
        }
    }
}

// ---------------------------------------------------------------------------
// Merged step kernel: blocks [0,n2) = LSTM2 step t ; [n2,...) = LSTM1 step t+1
// (independent given h1(t), hln(t) precomputed).
// ---------------------------------------------------------------------------
__global__ __launch_bounds__(256, 3) void step_kernel(
    int n2, int has1, int has2,
    const float* __restrict__ hln,  const float* __restrict__ h2r, float* __restrict__ h2w,
    float* __restrict__ c2, const short* __restrict__ w2c, const float* __restrict__ b2,
    const float* __restrict__ xlnt, const float* __restrict__ h1r, float* __restrict__ h1w,
    float* __restrict__ c1, const short* __restrict__ w1c, const float* __restrict__ b1)
{
    __shared__ __align__(16) char smem[46080];
    int bid = blockIdx.x;
    if (bid < n2) {
        // LSTM2: phase1 = W2 on hln (36x36, VALID->32x32), phase2 = U2 on h2
        lstm_step_core<64, 0, 50, 8, false, 50, 8, 32, 32>(
            bid, hln, 82944, 36, 36, h2r, w2c, b2, c2, h2w, has2, smem);
    } else {
        // LSTM1: phase1 = W1 on xln frame (40x40, VALID->36x36), phase2 = U1 on h1
        lstm_step_core<16, 0, 13, 10, true, 50, 9, 36, 36>(
            bid - n2, xlnt, 409600, 40, 40, h1r, w1c, b1, c1, h1w, has1, smem);
    }
}

// ---------------------------------------------------------------------------
// Final: mean over 32x32 pixels, dot dw[64], +db, *0.1
// ---------------------------------------------------------------------------
__global__ void pool_dot_kernel(const float* __restrict__ h, const float* __restrict__ dw,
                                const float* __restrict__ db, float* __restrict__ out)
{
    int b = blockIdx.x;
    __shared__ float sdw[64];
    if (threadIdx.x < 64) sdw[threadIdx.x] = dw[threadIdx.x];
    __syncthreads();
    float partial = 0.f;
    const float* hb = h + (size_t)b * 1024 * 64;
    for (int p = threadIdx.x; p < 1024; p += 256) {
        const float* hp = hb + (size_t)p * 64;
        #pragma unroll
        for (int f = 0; f < 64; f += 4) {
            float4 hv = *(const float4*)(hp + f);
            partial += hv.x * sdw[f] + hv.y * sdw[f + 1] + hv.z * sdw[f + 2] + hv.w * sdw[f + 3];
        }
    }
    #pragma unroll
    for (int o = 32; o > 0; o >>= 1) partial += __shfl_xor(partial, o);
    __shared__ float ws[4];
    if ((threadIdx.x & 63) == 0) ws[threadIdx.x >> 6] = partial;
    __syncthreads();
    if (threadIdx.x == 0) {
        float tot = ws[0] + ws[1] + ws[2] + ws[3];
        out[b] = (tot * (1.f / 1024.f) + db[0]) * 0.1f;
    }
}

// ---------------------------------------------------------------------------
// Orchestration: A(0) -> ln64(0) -> [ M(t)=C(t)+A(t+1) -> ln64(t+1) ]x15
//                -> C(15) -> pool.  2 launches per step.
// ---------------------------------------------------------------------------
extern "C" void kernel_launch(void* const* d_in, const int* in_sizes, int n_in,
                              void* d_out, int out_size, void* d_ws, size_t ws_size,
                              hipStream_t stream)
{
    const float* x   = (const float*)d_in[0];
    const float* lg1 = (const float*)d_in[1];
    const float* lb1 = (const float*)d_in[2];
    const float* W1  = (const float*)d_in[3];
    const float* U1  = (const float*)d_in[4];
    const float* b1  = (const float*)d_in[5];
    const float* lg2 = (const float*)d_in[6];
    const float* lb2 = (const float*)d_in[7];
    const float* W2  = (const float*)d_in[8];
    const float* U2  = (const float*)d_in[9];
    const float* b2  = (const float*)d_in[10];
    const float* dw  = (const float*)d_in[11];
    const float* db  = (const float*)d_in[12];
    float* out = (float*)d_out;

    constexpr int B = 8, T = 16;
    constexpr int P1 = 36 * 36, P2 = 32 * 32;

    float* w = (float*)d_ws;
    size_t off = 0;
    float* xln = w + off; off += (size_t)B * T * 40 * 40 * 16;  // 3,276,800
    float* h1a = w + off; off += (size_t)B * P1 * 64;
    float* h1b = w + off; off += (size_t)B * P1 * 64;
    float* c1  = w + off; off += (size_t)B * P1 * 64;
    float* hln = w + off; off += (size_t)B * P1 * 64;
    float* h2a = w + off; off += (size_t)B * P2 * 64;
    float* h2b = w + off; off += (size_t)B * P2 * 64;
    float* c2  = w + off; off += (size_t)B * P2 * 64;
    short* w1c = (short*)(w + off); off += (size_t)63 * 8192 / 2;   // 13 W1 + 50 U1 chunks
    short* w2c = (short*)(w + off); off += (size_t)100 * 8192 / 2;  // 50 W2 + 50 U2 chunks
    // total ~8.2M floats = 33 MB

    float* h1buf[2] = { h1a, h1b };
    float* h2buf[2] = { h2a, h2b };

    // one-time transforms
    ln16_kernel<<<800, 256, 0, stream>>>(x, lg1, lb1, xln, 204800);
    prep_w_perm<<<416, 256, 0, stream>>>(W1, w1c, 400, 13);
    prep_w_perm<<<1600, 256, 0, stream>>>(U1, w1c + (size_t)13 * 8192, 1600, 50);
    prep_w_perm<<<1600, 256, 0, stream>>>(W2, w2c, 1600, 50);
    prep_w_perm<<<1600, 256, 0, stream>>>(U2, w2c + (size_t)50 * 8192, 1600, 50);

    constexpr int NB1 = 11 * 4 * B;   // 352 LSTM1 blocks
    constexpr int NB2 = 8 * 4 * B;    // 256 LSTM2 blocks

    // A(0): LSTM1 step 0 only
    step_kernel<<<NB1, 256, 0, stream>>>(
        0, 0, 0,
        hln, h2buf[1], h2buf[0], c2, w2c, b2,
        xln, h1buf[1], h1buf[0], c1, w1c, b1);
    ln64_kernel<<<2592, 256, 0, stream>>>(h1buf[0], lg2, lb2, hln, B * P1);

    // M(t) = LSTM2 step t (blocks 0..255) + LSTM1 step t+1 (blocks 256..607)
    for (int t = 0; t < T - 1; ++t) {
        step_kernel<<<NB2 + NB1, 256, 0, stream>>>(
            NB2, 1, (t > 0) ? 1 : 0,
            hln, h2buf[(t + 1) & 1], h2buf[t & 1], c2, w2c, b2,
            xln + (size_t)(t + 1) * 25600, h1buf[t & 1], h1buf[(t + 1) & 1], c1, w1c, b1);
        ln64_kernel<<<2592, 256, 0, stream>>>(h1buf[(t + 1) & 1], lg2, lb2, hln, B * P1);
    }

    // C(15): LSTM2 final step
    step_kernel<<<NB2, 256, 0, stream>>>(
        NB2, 1, 1,
        hln, h2buf[0], h2buf[1], c2, w2c, b2,
        xln, h1buf[1], h1buf[0], c1, w1c, b1);

    pool_dot_kernel<<<B, 256, 0, stream>>>(h2buf[1], dw, db, out);
}

// Round 8
// 871.067 us; speedup vs baseline: 9.8033x; 1.0984x over previous
//
#include <hip/hip_runtime.h>
#include <hip/hip_bf16.h>
#include <cstddef>

#define LN_EPS 1e-3f

typedef short bf16x8 __attribute__((ext_vector_type(8)));
typedef float f32x4 __attribute__((ext_vector_type(4)));

__device__ __forceinline__ unsigned short f2bf(float f) {
    __hip_bfloat16 b = __float2bfloat16(f);
    unsigned short u;
    __builtin_memcpy(&u, &b, 2);
    return u;
}

__device__ __forceinline__ float bf2f(short u) {
    unsigned int x = ((unsigned int)(unsigned short)u) << 16;
    float f;
    __builtin_memcpy(&f, &x, 4);
    return f;
}

__device__ __forceinline__ float hsig(float x) {
    return fminf(fmaxf(fmaf(x, 0.2f, 0.5f), 0.f), 1.f);
}

// ---------------------------------------------------------------------------
// LayerNorm over last dim C=16, fp32 in -> bf16 out (one thread per row)
// ---------------------------------------------------------------------------
__global__ void ln16_kernel(const float* __restrict__ x, const float* __restrict__ g,
                            const float* __restrict__ b, short* __restrict__ y, int rows)
{
    int r = blockIdx.x * 256 + threadIdx.x;
    if (r >= rows) return;
    const float4* xr = (const float4*)(x + (size_t)r * 16);
    float v[16];
    *(float4*)(v + 0)  = xr[0];
    *(float4*)(v + 4)  = xr[1];
    *(float4*)(v + 8)  = xr[2];
    *(float4*)(v + 12) = xr[3];
    float mu = 0.f;
    #pragma unroll
    for (int i = 0; i < 16; ++i) mu += v[i];
    mu *= (1.f / 16.f);
    float var = 0.f;
    #pragma unroll
    for (int i = 0; i < 16; ++i) { float d = v[i] - mu; var += d * d; }
    var *= (1.f / 16.f);
    float rs = rsqrtf(var + LN_EPS);
    union { bf16x8 v8; unsigned short u[8]; } p0, p1;
    #pragma unroll
    for (int i = 0; i < 8; ++i)  p0.u[i] = f2bf((v[i] - mu) * rs * g[i] + b[i]);
    #pragma unroll
    for (int i = 0; i < 8; ++i)  p1.u[i] = f2bf((v[8 + i] - mu) * rs * g[8 + i] + b[8 + i]);
    bf16x8* yr = (bf16x8*)(y + (size_t)r * 16);
    yr[0] = p0.v8;
    yr[1] = p1.v8;
}

// ---------------------------------------------------------------------------
// Weight prep with GATE-INTERLEAVED cout permutation:
//   co' = q*64 + wn*32 + gate*8 + fl  <-  co_orig = gate*64 + (q*16+wn*8+fl)
// fp32 [K][256] -> bf16 [chunk][256 co'][32 k], zero-padded k >= K.
// ---------------------------------------------------------------------------
__global__ void prep_w_perm(const float* __restrict__ w, short* __restrict__ o, int K, int NC)
{
    int e = blockIdx.x * 256 + threadIdx.x;
    int tot = NC * 32 * 256;
    if (e >= tot) return;
    int cop = e & 255;
    int k   = e >> 8;
    int qq   = cop >> 6;
    int wn   = (cop >> 5) & 1;
    int gate = (cop >> 3) & 3;
    int fl   = cop & 7;
    int fg = qq * 16 + wn * 8 + fl;
    int co_orig = gate * 64 + fg;
    float v = (k < K) ? w[(size_t)k * 256 + co_orig] : 0.f;
    int chunk = k >> 5, kk = k & 31;
    o[((size_t)chunk * 256 + cop) * 32 + kk] = (short)f2bf(v);
}

// ---------------------------------------------------------------------------
// Stage bf16 patch rows [0,PRN): global bf16 -> bf16 XOR-swizzled LDS.
// DOLN: fused LayerNorm-64 (8-lane octet shfl stats). Requires TOTG % 256 == 0
// when DOLN (holds: LSTM2 phase1 8*36*8 = 2304).
// ---------------------------------------------------------------------------
template<int CIN, int PAD, int PRN, int PW, bool ZEROROW, bool DOLN>
__device__ __forceinline__ void stage_patch(char* smem, const short* __restrict__ inN,
                                            int IH, int IW, int r0,
                                            const float* __restrict__ lg,
                                            const float* __restrict__ lb)
{
    constexpr int GPP = CIN / 8;
    constexpr int SH  = (CIN == 64) ? 7 : 6;
    constexpr int TOTG = PRN * PW * GPP;
    const int tid = threadIdx.x;
    for (int gg = tid; gg < TOTG; gg += 256) {
        int pix = gg / GPP;
        int cig = gg % GPP;
        int pr = pix / PW, pc = pix % PW;
        int gy = r0 - PAD + pr;
        int gx = pc - PAD;
        bool ok = (gy >= 0) & (gy < IH) & (gx >= 0) & (gx < IW);
        if (ZEROROW && pr == PRN - 1) ok = false;   // zero row for K-pad taps
        bf16x8 v;
        #pragma unroll
        for (int i = 0; i < 8; ++i) v[i] = 0;
        if (ok) v = *(const bf16x8*)(inN + ((size_t)gy * IW + gx) * CIN + cig * 8);
        if (DOLN) {
            float f[8];
            #pragma unroll
            for (int i = 0; i < 8; ++i) f[i] = bf2f(v[i]);
            float s = 0.f;
            #pragma unroll
            for (int i = 0; i < 8; ++i) s += f[i];
            s += __shfl_xor(s, 1); s += __shfl_xor(s, 2); s += __shfl_xor(s, 4);
            float mu = s * (1.f / 64.f);
            float q = 0.f;
            #pragma unroll
            for (int i = 0; i < 8; ++i) { float d = f[i] - mu; q += d * d; }
            q += __shfl_xor(q, 1); q += __shfl_xor(q, 2); q += __shfl_xor(q, 4);
            float rs = rsqrtf(q * (1.f / 64.f) + LN_EPS);
            union { bf16x8 v8; unsigned short u[8]; } pk;
            #pragma unroll
            for (int i = 0; i < 8; ++i) {
                int ch = cig * 8 + i;
                pk.u[i] = f2bf((f[i] - mu) * rs * lg[ch] + lb[ch]);
            }
            v = pk.v8;
        }
        int ad = (pix * CIN + cig * 8) * 2;
        ad ^= ((ad >> SH) & 7) << 4;
        *(bf16x8*)(smem + ad) = v;
    }
}

// ---------------------------------------------------------------------------
// K-loop over NC chunks: A-frags from swizzled LDS, B-frags global->reg with
// DEPTH-2 chunk prefetch ([chunk][co'][32k] == B-frag layout). No barriers.
// ---------------------------------------------------------------------------
template<int CIN, int PW, int NC>
__device__ __forceinline__ void kloop(const char* smem, const short* __restrict__ wbase,
                                      int colane, int g, const int* base_m, f32x4 (&acc)[4][2])
{
    constexpr int SH = (CIN == 64) ? 7 : 6;
    const short* wlp = wbase + (size_t)colane * 32 + g * 8;
    bf16x8 c0a = *(const bf16x8*)wlp;
    bf16x8 c0b = *(const bf16x8*)(wlp + 512);
    bf16x8 c1a, c1b;
    if (NC > 1) {
        c1a = *(const bf16x8*)(wlp + 8192);
        c1b = *(const bf16x8*)(wlp + 8192 + 512);
    }
    int dy0 = 0, dx0 = 0, dy1 = 0, dx1 = 1;
    for (int c = 0; c < NC; ++c) {
        bf16x8 n2a, n2b;
        const bool pf = (c + 2 < NC);
        if (pf) {
            const short* wnx = wlp + (size_t)(c + 2) * 8192;
            n2a = *(const bf16x8*)wnx;
            n2b = *(const bf16x8*)(wnx + 512);
        }
        int off;
        if (CIN == 64) {
            off = (dy0 * PW + dx0) * 128 + ((c & 1) << 6) + (g << 4);
        } else {
            int U0 = (dy0 * PW + dx0) * 32;
            int U1 = (dy1 * PW + dx1) * 32;
            off = ((g & 2) ? U1 : U0) + ((g & 1) << 4);
        }
        bf16x8 a[4];
        #pragma unroll
        for (int m = 0; m < 4; ++m) {
            int ad = base_m[m] + off;
            ad ^= ((ad >> SH) & 7) << 4;
            a[m] = *(const bf16x8*)(smem + ad);
        }
        #pragma unroll
        for (int m = 0; m < 4; ++m) {
            acc[m][0] = __builtin_amdgcn_mfma_f32_16x16x32_bf16(a[m], c0a, acc[m][0], 0, 0, 0);
            acc[m][1] = __builtin_amdgcn_mfma_f32_16x16x32_bf16(a[m], c0b, acc[m][1], 0, 0, 0);
        }
        c0a = c1a; c0b = c1b;
        if (pf) { c1a = n2a; c1b = n2b; }
        if (CIN == 64) {
            if (c & 1) { if (++dx0 == 5) { dx0 = 0; ++dy0; } }
        } else {
            dx0 += 2; if (dx0 >= 5) { dx0 -= 5; ++dy0; }
            dx1 += 2; if (dx1 >= 5) { dx1 -= 5; ++dy1; }
        }
    }
}

// ---------------------------------------------------------------------------
// One full ConvLSTM step for a (128px x 64co') tile with FUSED GATES:
//   phase1 (DOLN1 optionally fuses LayerNorm-64): W-conv ; phase2: U-conv.
//   epilogue: gate exchange via shfl_xor(8); c fp32, h bf16.
// ---------------------------------------------------------------------------
template<int CIN1, int PAD1, int NC1, int PRN1, bool ZR1, bool DOLN1,
         int NC2, int PRN2, int OW, int OH>
__device__ void lstm_step_core(int lblk, const short* __restrict__ in1, size_t in1_bstride,
                               int IH1, int IW1,
                               const short* __restrict__ hprev,
                               const short* __restrict__ wts, const float* __restrict__ bias,
                               const float* __restrict__ lg, const float* __restrict__ lb,
                               float* __restrict__ cbuf, short* __restrict__ hbuf,
                               int has_rec, char* smem)
{
    constexpr int PW  = OW + 4;
    constexpr int OHW = OW * OH;
    constexpr int NTIL = (OHW + 127) / 128;
    constexpr bool FULL = (OHW % 128) == 0;

    const int tid  = threadIdx.x;
    const int tile = lblk % NTIL;
    const int q    = (lblk / NTIL) & 3;
    const int n    = lblk / (NTIL * 4);
    const int p0   = tile * 128;
    const int r0   = p0 / OW;
    const int co0  = q * 64;

    const int lane = tid & 63;
    const int wid  = tid >> 6;
    const int wm   = wid >> 1;
    const int wn   = wid & 1;
    const int lr   = lane & 15;
    const int g    = lane >> 4;

    int base1[4], base2[4];
    #pragma unroll
    for (int m = 0; m < 4; ++m) {
        int px = p0 + wm * 64 + m * 16 + lr;
        int r = px / OW;
        int x = px - r * OW;
        base1[m] = ((r - r0) * PW + x) * CIN1 * 2;
        base2[m] = ((r - r0) * PW + x) * 128;
    }

    f32x4 acc[4][2];
    #pragma unroll
    for (int m = 0; m < 4; ++m)
        #pragma unroll
        for (int nn = 0; nn < 2; ++nn)
            acc[m][nn] = (f32x4){0.f, 0.f, 0.f, 0.f};

    // ---- phase 1: W-conv (optionally with fused LN on the staged input) ----
    stage_patch<CIN1, PAD1, PRN1, PW, ZR1, DOLN1>(
        smem, in1 + (size_t)n * in1_bstride, IH1, IW1, r0, lg, lb);
    __syncthreads();
    kloop<CIN1, PW, NC1>(smem, wts, co0 + wn * 32 + lr, g, base1, acc);

    // ---- phase 2: U-conv on previous h (restage same LDS) ----
    if (has_rec) {
        __syncthreads();
        stage_patch<64, 2, PRN2, PW, false, false>(
            smem, hprev + (size_t)n * OHW * 64, OH, OW, r0, nullptr, nullptr);
        __syncthreads();
        kloop<64, PW, NC2>(smem, wts + (size_t)NC1 * 8192, co0 + wn * 32 + lr, g, base2, acc);
    }

    // ---- fused gate epilogue ----
    const int fg = q * 16 + wn * 8 + (lr & 7);
    const bool low = (lr & 8) == 0;
    const float b0  = bias[(lr >> 3) * 64 + fg];         // gate 0/1 (i or f)
    const float b1v = bias[(2 + (lr >> 3)) * 64 + fg];   // gate 2/3 (cg or o)
    float* cN = cbuf + (size_t)n * OHW * 64;
    short* hN = hbuf + (size_t)n * OHW * 64;
    #pragma unroll
    for (int m = 0; m < 4; ++m) {
        int pxb = p0 + wm * 64 + m * 16 + g * 4;
        #pragma unroll
        for (int j = 0; j < 4; ++j) {
            int px = pxb + j;
            float a0 = acc[m][0][j] + b0;
            float a1 = acc[m][1][j] + b1v;
            float q0 = __shfl_xor(a0, 8);
            float q1 = __shfl_xor(a1, 8);
            float iv  = low ? a0 : q0;
            float fv  = low ? q0 : a0;
            float cgv = low ? a1 : q1;
            float ov  = low ? q1 : a1;
            bool valid = FULL || (px < OHW);
            int addr = px * 64 + fg;
            float cp = 0.f;
            if (has_rec && valid) cp = cN[addr];
            float cn = fmaf(hsig(fv), cp, hsig(iv) * tanhf(cgv));
            float hv = hsig(ov) * tanhf(cn);
            if (valid) {
                if (low) cN[addr] = cn;
                else     hN[addr] = (short)f2bf(hv);
            }
        }
    }
}

// ---------------------------------------------------------------------------
// Merged step kernel: blocks [0,n2) = LSTM2 step t (reads LN(h1) inline);
// blocks [n2,...) = LSTM1 step t+1.
// ---------------------------------------------------------------------------
__global__ __launch_bounds__(256, 3) void step_kernel(
    int n2, int has1, int has2,
    const short* __restrict__ h1r, const short* __restrict__ h2r, short* __restrict__ h2w,
    float* __restrict__ c2, const short* __restrict__ w2c, const float* __restrict__ b2,
    const float* __restrict__ lg2, const float* __restrict__ lb2,
    const short* __restrict__ xlnt, short* __restrict__ h1w,
    float* __restrict__ c1, const short* __restrict__ w1c, const float* __restrict__ b1)
{
    __shared__ __align__(16) char smem[46080];
    int bid = blockIdx.x;
    if (bid < n2) {
        // LSTM2: phase1 = W2 on LN(h1(t)) (36x36 VALID -> 32x32), phase2 = U2 on h2
        lstm_step_core<64, 0, 50, 8, false, true, 50, 8, 32, 32>(
            bid, h1r, 82944, 36, 36, h2r, w2c, b2, lg2, lb2, c2, h2w, has2, smem);
    } else {
        // LSTM1: phase1 = W1 on xln frame (40x40 VALID -> 36x36), phase2 = U1 on h1
        lstm_step_core<16, 0, 13, 10, true, false, 50, 9, 36, 36>(
            bid - n2, xlnt, 409600, 40, 40, h1r, w1c, b1, nullptr, nullptr,
            c1, h1w, has1, smem);
    }
}

// ---------------------------------------------------------------------------
// Final: mean over 32x32 pixels (bf16 h), dot dw[64], +db, *0.1
// ---------------------------------------------------------------------------
__global__ void pool_dot_kernel(const short* __restrict__ h, const float* __restrict__ dw,
                                const float* __restrict__ db, float* __restrict__ out)
{
    int b = blockIdx.x;
    __shared__ float sdw[64];
    if (threadIdx.x < 64) sdw[threadIdx.x] = dw[threadIdx.x];
    __syncthreads();
    float partial = 0.f;
    const short* hb = h + (size_t)b * 1024 * 64;
    for (int p = threadIdx.x; p < 1024; p += 256) {
        const short* hp = hb + (size_t)p * 64;
        #pragma unroll
        for (int f = 0; f < 64; f += 8) {
            bf16x8 hv = *(const bf16x8*)(hp + f);
            #pragma unroll
            for (int i = 0; i < 8; ++i) partial += bf2f(hv[i]) * sdw[f + i];
        }
    }
    #pragma unroll
    for (int o = 32; o > 0; o >>= 1) partial += __shfl_xor(partial, o);
    __shared__ float ws[4];
    if ((threadIdx.x & 63) == 0) ws[threadIdx.x >> 6] = partial;
    __syncthreads();
    if (threadIdx.x == 0) {
        float tot = ws[0] + ws[1] + ws[2] + ws[3];
        out[b] = (tot * (1.f / 1024.f) + db[0]) * 0.1f;
    }
}

// ---------------------------------------------------------------------------
// Orchestration: A(0) -> [ M(t) = LSTM2(t) + LSTM1(t+1) ] x15 -> C(15) -> pool.
// ONE launch per step (LN64 fused into LSTM2 staging).
// ---------------------------------------------------------------------------
extern "C" void kernel_launch(void* const* d_in, const int* in_sizes, int n_in,
                              void* d_out, int out_size, void* d_ws, size_t ws_size,
                              hipStream_t stream)
{
    const float* x   = (const float*)d_in[0];
    const float* lg1 = (const float*)d_in[1];
    const float* lb1 = (const float*)d_in[2];
    const float* W1  = (const float*)d_in[3];
    const float* U1  = (const float*)d_in[4];
    const float* b1  = (const float*)d_in[5];
    const float* lg2 = (const float*)d_in[6];
    const float* lb2 = (const float*)d_in[7];
    const float* W2  = (const float*)d_in[8];
    const float* U2  = (const float*)d_in[9];
    const float* b2  = (const float*)d_in[10];
    const float* dw  = (const float*)d_in[11];
    const float* db  = (const float*)d_in[12];
    float* out = (float*)d_out;

    constexpr int B = 8, T = 16;
    constexpr int P1 = 36 * 36, P2 = 32 * 32;

    char* wsb = (char*)d_ws;
    size_t off = 0;
    auto alloc_s = [&](size_t nshort) { short* p = (short*)(wsb + off); off += nshort * 2; return p; };
    auto alloc_f = [&](size_t nfloat) { off = (off + 15) & ~(size_t)15; float* p = (float*)(wsb + off); off += nfloat * 4; return p; };

    short* xln = alloc_s((size_t)B * T * 40 * 40 * 16);   // bf16, 6.5 MB
    short* h1a = alloc_s((size_t)B * P1 * 64);
    short* h1b = alloc_s((size_t)B * P1 * 64);
    short* h2a = alloc_s((size_t)B * P2 * 64);
    short* h2b = alloc_s((size_t)B * P2 * 64);
    short* w1c = alloc_s((size_t)63 * 8192);              // 13 W1 + 50 U1 chunks
    short* w2c = alloc_s((size_t)100 * 8192);             // 50 W2 + 50 U2 chunks
    float* c1  = alloc_f((size_t)B * P1 * 64);
    float* c2  = alloc_f((size_t)B * P2 * 64);
    // total ~20 MB

    short* h1buf[2] = { h1a, h1b };
    short* h2buf[2] = { h2a, h2b };

    // one-time transforms
    ln16_kernel<<<800, 256, 0, stream>>>(x, lg1, lb1, xln, 204800);
    prep_w_perm<<<416, 256, 0, stream>>>(W1, w1c, 400, 13);
    prep_w_perm<<<1600, 256, 0, stream>>>(U1, w1c + (size_t)13 * 8192, 1600, 50);
    prep_w_perm<<<1600, 256, 0, stream>>>(W2, w2c, 1600, 50);
    prep_w_perm<<<1600, 256, 0, stream>>>(U2, w2c + (size_t)50 * 8192, 1600, 50);

    constexpr int NB1 = 11 * 4 * B;   // 352 LSTM1 blocks
    constexpr int NB2 = 8 * 4 * B;    // 256 LSTM2 blocks

    // A(0): LSTM1 step 0 only
    step_kernel<<<NB1, 256, 0, stream>>>(
        0, 0, 0,
        h1buf[1], h2buf[1], h2buf[0], c2, w2c, b2, lg2, lb2,
        xln, h1buf[0], c1, w1c, b1);

    // M(t): LSTM2 step t (reads LN(h1(t)) inline) + LSTM1 step t+1
    for (int t = 0; t < T - 1; ++t) {
        step_kernel<<<NB2 + NB1, 256, 0, stream>>>(
            NB2, 1, (t > 0) ? 1 : 0,
            h1buf[t & 1], h2buf[(t + 1) & 1], h2buf[t & 1], c2, w2c, b2, lg2, lb2,
            xln + (size_t)(t + 1) * 25600, h1buf[(t + 1) & 1], c1, w1c, b1);
    }

    // C(15): LSTM2 final step (h1(15) is in h1buf[1])
    step_kernel<<<NB2, 256, 0, stream>>>(
        NB2, 1, 1,
        h1buf[1], h2buf[0], h2buf[1], c2, w2c, b2, lg2, lb2,
        xln, h1buf[0], c1, w1c, b1);

    pool_dot_kernel<<<B, 256, 0, stream>>>(h2buf[1], dw, db, out);
}